// Round 9
// baseline (986.555 us; speedup 1.0000x reference)
//
#include <hip/hip_runtime.h>
#include <stdint.h>

#define BATCH   8
#define LEN0    8192
#define EMB     768
#define POOLED  512    // LEN0 >> 4
#define GRID    512    // k_pipe blocks; __launch_bounds__(256,4) -> capacity 1024 >= 512
#define NJC     16     // j-chunks per level in rank phase
#define PL      (BATCH * LEN0)

struct __align__(16) Rec { uint32_t iA, iB; float w0, w1; };

// ---------------------------------------------------------------------------
// ws layout (bytes):
//   scA    : BATCH*LEN0 f32        @ 0x000000  (256 KiB)
//   scB    : BATCH*LEN0 f32        @ 0x040000
//   rank16 : BATCH*LEN0 u16        @ 0x080000  (128 KiB)
//   ior16  : BATCH*LEN0 u16        @ 0x0A0000
//   rec0   : 4096*8 Rec            @ 0x0C0000  (512 KiB)
//   rec1   : 2048*8 Rec            @ 0x140000  (256 KiB)
//   rec2   : 1024*8 Rec            @ 0x180000  (128 KiB)
//   rec3   :  512*8 Rec            @ 0x1A0000  ( 64 KiB)
//   rankp  : NJC planes BATCH*LEN0 u16 @ 0x1C0000 (2 MiB)
//   bar    : 2 u32                 @ 0x3C0000  (memsetAsync'd each call)
// ---------------------------------------------------------------------------

// Bit-faithful replication of numpy's SIMD float32 exp — DO NOT TOUCH.
// (Round 5 proved this exact sequence makes ranks match the numpy golden.)
__device__ __forceinline__ float npy_expf(float x) {
    const float q = rintf(__fmul_rn(x, 1.44269504088896341f)); // LOG2EF
    float r = __fmaf_rn(q, -0.693359375f, x);       // fnmadd(q, C1, x)
    r = __fmaf_rn(q, 2.12194440e-4f, r);            // fnmadd(q, C2, x)
    const float r2 = __fmul_rn(r, r);
    float p = 1.9875691500E-4f;
    p = __fmaf_rn(p, r, 1.3981999507E-3f);
    p = __fmaf_rn(p, r, 8.3334519073E-3f);
    p = __fmaf_rn(p, r, 4.1665795894E-2f);
    p = __fmaf_rn(p, r, 1.6666665459E-1f);
    p = __fmaf_rn(p, r, 5.0000001201E-1f);
    p = __fmaf_rn(p, r2, r);
    p = __fadd_rn(p, 1.0f);
    const int qi = (int)q;
    const float sc = __uint_as_float((uint32_t)((qi + 127) << 23));
    return __fmul_rn(p, sc);
}

// Generation-based software grid barrier. bar[0]=arrive count, bar[1]=gen.
// Release-acquire chain: arriver RMW-releases bar[0]; last arriver acquires
// the chain, resets count, release-bumps bar[1]; waiters acquire bar[1].
__device__ __forceinline__ void gbar(uint32_t* bar) {
    __syncthreads();
    if (threadIdx.x == 0) {
        const uint32_t gen = __hip_atomic_load(&bar[1], __ATOMIC_RELAXED,
                                               __HIP_MEMORY_SCOPE_AGENT);
        const uint32_t n = __hip_atomic_fetch_add(&bar[0], 1u, __ATOMIC_ACQ_REL,
                                                  __HIP_MEMORY_SCOPE_AGENT);
        if (n == GRID - 1) {
            __hip_atomic_store(&bar[0], 0u, __ATOMIC_RELAXED,
                               __HIP_MEMORY_SCOPE_AGENT);
            __hip_atomic_fetch_add(&bar[1], 1u, __ATOMIC_RELEASE,
                                   __HIP_MEMORY_SCOPE_AGENT);
        } else {
            while (__hip_atomic_load(&bar[1], __ATOMIC_ACQUIRE,
                                     __HIP_MEMORY_SCOPE_AGENT) == gen)
                __builtin_amdgcn_s_sleep(2);
        }
    }
    __syncthreads();
}

// Rank phase: chunked rank-by-count, 4 i's/thread vs staged j-chunk.
// Stable (ascending-index) ties. Partial counts (<= L/NJC) -> rankp planes.
template<int L>
__device__ __forceinline__ void rank_phase(const float* __restrict__ sc,
                                           uint16_t* __restrict__ rankp,
                                           float* keys, int bid, int tid) {
    constexpr int NIB   = L / 1024;        // i-tasks per (jc,b): 8,4,2,1
    constexpr int C     = L / NJC;         // 512,256,128,64
    constexpr int TASKS = NIB * NJC * BATCH;
    for (int task = bid; task < TASKS; task += GRID) {
        const int b     = task & 7;
        const int t     = task >> 3;
        const int ib    = t % NIB;
        const int jc    = t / NIB;
        const int base  = b * LEN0;
        const int ibase = ib * 1024;
        const int jb    = jc * C;
        __syncthreads();                   // keys reuse guard across tasks
        for (int j = tid; j < C; j += 256)
            keys[j] = sc[base + jb + j];
        __syncthreads();

        const int i0 = ibase + tid * 4;
        const float4 mev = *(const float4*)&sc[base + i0];
        const float me[4] = {mev.x, mev.y, mev.z, mev.w};
        uint32_t cnt[4] = {0, 0, 0, 0};
        if (jb + C <= ibase) {             // all j < i: ties count
            for (int j = 0; j < C; j += 4) {
                const float4 kv = *(const float4*)&keys[j];
                #pragma unroll
                for (int m = 0; m < 4; m++)
                    cnt[m] += (kv.x >= me[m]) + (kv.y >= me[m]) +
                              (kv.z >= me[m]) + (kv.w >= me[m]);
            }
        } else if (jb >= ibase + 1024) {   // all j > i: ties don't count
            for (int j = 0; j < C; j += 4) {
                const float4 kv = *(const float4*)&keys[j];
                #pragma unroll
                for (int m = 0; m < 4; m++)
                    cnt[m] += (kv.x > me[m]) + (kv.y > me[m]) +
                              (kv.z > me[m]) + (kv.w > me[m]);
            }
        } else {                           // diagonal: full stable predicate
            for (int j = 0; j < C; j += 4) {
                const float4 kv = *(const float4*)&keys[j];
                const int jj = jb + j;
                #pragma unroll
                for (int m = 0; m < 4; m++) {
                    const int i = i0 + m;
                    cnt[m] += ((kv.x > me[m]) || (kv.x == me[m] && (jj    ) < i))
                            + ((kv.y > me[m]) || (kv.y == me[m] && (jj + 1) < i))
                            + ((kv.z > me[m]) || (kv.z == me[m] && (jj + 2) < i))
                            + ((kv.w > me[m]) || (kv.w == me[m] && (jj + 3) < i));
                }
            }
        }
        *(ushort4*)&rankp[(size_t)jc * PL + base + i0] =
            make_ushort4((uint16_t)cnt[0], (uint16_t)cnt[1],
                         (uint16_t)cnt[2], (uint16_t)cnt[3]);
    }
}

// Sum NJC partial planes -> rank16; scatter inverse permutation ior16.
template<int L>
__device__ __forceinline__ void sumscatter_phase(const uint16_t* __restrict__ rankp,
                                                 uint16_t* __restrict__ rank16,
                                                 uint16_t* __restrict__ ior16,
                                                 int bid, int tid) {
    constexpr int TASKS = (L / 1024) * BATCH;
    for (int task = bid; task < TASKS; task += GRID) {
        const int b    = task & 7;
        const int ib   = task >> 3;
        const int base = b * LEN0;
        const int i0   = ib * 1024 + tid * 4;
        uint32_t r0 = 0, r1 = 0, r2 = 0, r3 = 0;
        #pragma unroll
        for (int c = 0; c < NJC; c++) {
            const ushort4 v = *(const ushort4*)&rankp[(size_t)c * PL + base + i0];
            r0 += v.x; r1 += v.y; r2 += v.z; r3 += v.w;
        }
        *(ushort4*)&rank16[base + i0] =
            make_ushort4((uint16_t)r0, (uint16_t)r1, (uint16_t)r2, (uint16_t)r3);
        ior16[base + r0] = (uint16_t)(i0);
        ior16[base + r1] = (uint16_t)(i0 + 1);
        ior16[base + r2] = (uint16_t)(i0 + 2);
        ior16[base + r3] = (uint16_t)(i0 + 3);
    }
}

// One block per batch: flag scan (SORT_BACK dst), softmax (NUMERICS FROZEN,
// round 5), new scores, pair record write.
template<int L>
__device__ __forceinline__ void scanpair_phase(const float* __restrict__ sc_cur,
                                               float* __restrict__ sc_nxt,
                                               const uint16_t* __restrict__ rank16,
                                               const uint16_t* __restrict__ ior16,
                                               Rec* __restrict__ rec,
                                               uint32_t* part, int bid, int tid) {
    if (bid >= BATCH) return;
    const int b    = bid;
    const int base = b * LEN0;
    constexpr int R = L / 256;            // 32,16,8,4
    constexpr uint32_t half = L / 2;
    const int i0 = tid * R;

    uint16_t rr[R];
    #pragma unroll
    for (int m = 0; m < R; m += 4)
        *(ushort4*)&rr[m] = *(const ushort4*)&rank16[base + i0 + m];

    uint32_t loc = 0;
    #pragma unroll
    for (int m = 0; m < R; m++) loc += (rr[m] < half) ? 1u : 0u;
    part[tid] = loc;
    __syncthreads();
    for (int off = 1; off < 256; off <<= 1) {    // Hillis-Steele inclusive
        uint32_t v = part[tid];
        uint32_t add = (tid >= off) ? part[tid - off] : 0u;
        __syncthreads();
        part[tid] = v + add;
        __syncthreads();
    }
    uint32_t dst = (tid > 0) ? part[tid - 1] : 0u;

    #pragma unroll
    for (int m = 0; m < R; m++) {
        const uint32_t r = rr[m];
        if (r >= half) continue;
        const int i = i0 + m;
        const uint32_t p = ior16[base + (L - 1) - r];

        const float s0 = sc_cur[base + i];
        const float s1 = sc_cur[base + p];
        // np.power(2.0, s): glibc powf (correctly rounded); exp2 in double
        // rounded to f32 reproduces it.
        const float p0 = (float)exp2((double)s0);
        const float p1 = (float)exp2((double)s1);
        const float mx = fmaxf(p0, p1);
        const float d0 = __fsub_rn(p0, mx);
        const float d1 = __fsub_rn(p1, mx);
        const float e0 = npy_expf(d0);
        const float e1 = npy_expf(d1);
        const float den = __fadd_rn(e0, e1);
        const float w0 = __fdiv_rn(e0, den);
        const float w1 = __fdiv_rn(e1, den);
        sc_nxt[base + dst] = __fadd_rn(__fmul_rn(s0, w0), __fmul_rn(s1, w1));

        Rec rc; rc.iA = (uint32_t)i; rc.iB = p; rc.w0 = w0; rc.w1 = w1;
        rec[(size_t)b * half + dst] = rc;
        dst++;
    }
}

// Whole score pipeline: 4 x (rank | B | sumscatter | B | scanpair | B).
__global__ __launch_bounds__(256, 4)
void k_pipe(const float* __restrict__ scores,
            float* __restrict__ scA, float* __restrict__ scB,
            uint16_t* __restrict__ rank16, uint16_t* __restrict__ ior16,
            Rec* __restrict__ rec0, Rec* __restrict__ rec1,
            Rec* __restrict__ rec2, Rec* __restrict__ rec3,
            uint16_t* __restrict__ rankp, uint32_t* __restrict__ bar) {
    __shared__ float    keys[512];
    __shared__ uint32_t part[256];
    const int bid = blockIdx.x;
    const int tid = threadIdx.x;

    rank_phase<8192>(scores, rankp, keys, bid, tid);
    gbar(bar);
    sumscatter_phase<8192>(rankp, rank16, ior16, bid, tid);
    gbar(bar);
    scanpair_phase<8192>(scores, scA, rank16, ior16, rec0, part, bid, tid);
    gbar(bar);
    rank_phase<4096>(scA, rankp, keys, bid, tid);
    gbar(bar);
    sumscatter_phase<4096>(rankp, rank16, ior16, bid, tid);
    gbar(bar);
    scanpair_phase<4096>(scA, scB, rank16, ior16, rec1, part, bid, tid);
    gbar(bar);
    rank_phase<2048>(scB, rankp, keys, bid, tid);
    gbar(bar);
    sumscatter_phase<2048>(rankp, rank16, ior16, bid, tid);
    gbar(bar);
    scanpair_phase<2048>(scB, scA, rank16, ior16, rec2, part, bid, tid);
    gbar(bar);
    rank_phase<1024>(scA, rankp, keys, bid, tid);
    gbar(bar);
    sumscatter_phase<1024>(rankp, rank16, ior16, bid, tid);
    gbar(bar);
    scanpair_phase<1024>(scA, scB, rank16, ior16, rec3, part, bid, tid);
    // final scores in scB; pairing tree in rec0..rec3
}

// Final gather: expand 4-level pair tree -> 16 (idx, weight) leaves, then
// out[b,s,:] = sum_k w_k * emb[b, idx_k, :].
__global__ __launch_bounds__(192)
void k_merge(const float* __restrict__ emb,
             const Rec* __restrict__ rec0, const Rec* __restrict__ rec1,
             const Rec* __restrict__ rec2, const Rec* __restrict__ rec3,
             const float* __restrict__ sc_fin, float* __restrict__ out) {
    __shared__ uint32_t sl[2][16];
    __shared__ float    sw[2][16];
    const int s = blockIdx.x;
    const int b = blockIdx.y;
    const int d = threadIdx.x;

    if (d == 0) {
        const Rec r = rec3[b * 512 + s];
        sl[0][0] = r.iA; sl[0][1] = r.iB;
        sw[0][0] = r.w0; sw[0][1] = r.w1;
    }
    __syncthreads();
    if (d < 2) {
        const Rec r = rec2[b * 1024 + sl[0][d]];
        sl[1][2*d] = r.iA; sl[1][2*d+1] = r.iB;
        sw[1][2*d]   = __fmul_rn(sw[0][d], r.w0);
        sw[1][2*d+1] = __fmul_rn(sw[0][d], r.w1);
    }
    __syncthreads();
    if (d < 4) {
        const Rec r = rec1[b * 2048 + sl[1][d]];
        sl[0][2*d] = r.iA; sl[0][2*d+1] = r.iB;
        sw[0][2*d]   = __fmul_rn(sw[1][d], r.w0);
        sw[0][2*d+1] = __fmul_rn(sw[1][d], r.w1);
    }
    __syncthreads();
    if (d < 8) {
        const Rec r = rec0[b * 4096 + sl[0][d]];   // iA/iB = original rows
        sl[1][2*d] = r.iA; sl[1][2*d+1] = r.iB;
        sw[1][2*d]   = __fmul_rn(sw[0][d], r.w0);
        sw[1][2*d+1] = __fmul_rn(sw[0][d], r.w1);
    }
    __syncthreads();

    const float* ebase = emb + (size_t)b * LEN0 * EMB;
    float4 acc = make_float4(0.f, 0.f, 0.f, 0.f);
    #pragma unroll
    for (int k = 0; k < 16; k++) {
        const float4 v = *(const float4*)(ebase + (size_t)sl[1][k] * EMB + d * 4);
        const float wk = sw[1][k];
        acc.x += wk * v.x; acc.y += wk * v.y; acc.z += wk * v.z; acc.w += wk * v.w;
    }
    *(float4*)(out + ((size_t)b * POOLED + s) * EMB + d * 4) = acc;
    if (d == 0)
        out[(size_t)BATCH * POOLED * EMB + b * POOLED + s] = sc_fin[b * LEN0 + s];
}

extern "C" void kernel_launch(void* const* d_in, const int* in_sizes, int n_in,
                              void* d_out, int out_size, void* d_ws, size_t ws_size,
                              hipStream_t stream) {
    const float* embs   = (const float*)d_in[0];
    const float* scores = (const float*)d_in[1];
    float* out = (float*)d_out;
    char* ws = (char*)d_ws;

    float*    scA    = (float*)(ws + 0x000000);
    float*    scB    = (float*)(ws + 0x040000);
    uint16_t* rank16 = (uint16_t*)(ws + 0x080000);
    uint16_t* ior16  = (uint16_t*)(ws + 0x0A0000);
    Rec*      rec0   = (Rec*)(ws + 0x0C0000);
    Rec*      rec1   = (Rec*)(ws + 0x140000);
    Rec*      rec2   = (Rec*)(ws + 0x180000);
    Rec*      rec3   = (Rec*)(ws + 0x1A0000);
    uint16_t* rankp  = (uint16_t*)(ws + 0x1C0000);
    uint32_t* bar    = (uint32_t*)(ws + 0x3C0000);

    hipMemsetAsync(bar, 0, 2 * sizeof(uint32_t), stream);

    k_pipe<<<GRID, 256, 0, stream>>>(scores, scA, scB, rank16, ior16,
                                     rec0, rec1, rec2, rec3, rankp, bar);

    k_merge<<<dim3(POOLED, BATCH), 192, 0, stream>>>(embs, rec0, rec1, rec2, rec3,
                                                     scB, out);
}

// Round 10
// 278.962 us; speedup vs baseline: 3.5365x; 3.5365x over previous
//
#include <hip/hip_runtime.h>
#include <stdint.h>

#define BATCH   8
#define LEN0    8192
#define EMB     768
#define POOLED  512    // LEN0 >> 4
#define GB      64     // blocks per batch group
#define GRID    (BATCH * GB)   // 512; __launch_bounds__(256,4) -> capacity 1024
#define NJC     16     // j-chunks per level in rank phase
#define PL      (BATCH * LEN0)
#define FPAD    16     // u32 stride per sync flag (64B, avoids false sharing)

struct __align__(16) Rec { uint32_t iA, iB; float w0, w1; };

// ---------------------------------------------------------------------------
// ws layout (bytes):
//   scA    : BATCH*LEN0 f32        @ 0x000000  (256 KiB)
//   scB    : BATCH*LEN0 f32        @ 0x040000
//   rec0   : 4096*8 Rec            @ 0x0C0000  (512 KiB)
//   rec1   : 2048*8 Rec            @ 0x140000  (256 KiB)
//   rec2   : 1024*8 Rec            @ 0x180000  (128 KiB)
//   rec3   :  512*8 Rec            @ 0x1A0000  ( 64 KiB)
//   rankp  : NJC planes BATCH*LEN0 u16 @ 0x1C0000 (2 MiB)
//   sync   : flags[8][64]*FPAD + gens[8]*FPAD u32 @ 0x3C0000 (33 KiB, memset)
// ---------------------------------------------------------------------------

// Bit-faithful replication of numpy's SIMD float32 exp — DO NOT TOUCH.
// (Round 5 proved this exact sequence makes ranks match the numpy golden.)
__device__ __forceinline__ float npy_expf(float x) {
    const float q = rintf(__fmul_rn(x, 1.44269504088896341f)); // LOG2EF
    float r = __fmaf_rn(q, -0.693359375f, x);       // fnmadd(q, C1, x)
    r = __fmaf_rn(q, 2.12194440e-4f, r);            // fnmadd(q, C2, x)
    const float r2 = __fmul_rn(r, r);
    float p = 1.9875691500E-4f;
    p = __fmaf_rn(p, r, 1.3981999507E-3f);
    p = __fmaf_rn(p, r, 8.3334519073E-3f);
    p = __fmaf_rn(p, r, 4.1665795894E-2f);
    p = __fmaf_rn(p, r, 1.6666665459E-1f);
    p = __fmaf_rn(p, r, 5.0000001201E-1f);
    p = __fmaf_rn(p, r2, r);
    p = __fadd_rn(p, 1.0f);
    const int qi = (int)q;
    const float sc = __uint_as_float((uint32_t)((qi + 127) << 23));
    return __fmul_rn(p, sc);
}

__device__ __forceinline__ uint32_t relx_ld(uint32_t* p) {
    return __hip_atomic_load(p, __ATOMIC_RELAXED, __HIP_MEMORY_SCOPE_AGENT);
}
__device__ __forceinline__ void relx_st(uint32_t* p, uint32_t v) {
    __hip_atomic_store(p, v, __ATOMIC_RELAXED, __HIP_MEMORY_SCOPE_AGENT);
}

// Rank phase for one batch group: chunked rank-by-count, 4 i's/thread.
// Stable (ascending-index) ties. Partial counts -> rankp planes.
template<int L>
__device__ __forceinline__ void rank_group(const float* __restrict__ sc,
                                           uint16_t* __restrict__ rankp,
                                           float* keys, int batch, int sub, int tid) {
    constexpr int NIB   = L / 1024;        // i-tasks: 8,4,2,1
    constexpr int C     = L / NJC;         // 512,256,128,64
    constexpr int TASKS = NIB * NJC;
    const int base = batch * LEN0;
    for (int t = sub; t < TASKS; t += GB) {
        const int ib    = t % NIB;
        const int jc    = t / NIB;
        const int ibase = ib * 1024;
        const int jb    = jc * C;
        __syncthreads();                   // keys reuse guard across tasks
        for (int j = tid; j < C; j += 256)
            keys[j] = sc[base + jb + j];
        __syncthreads();

        const int i0 = ibase + tid * 4;
        const float4 mev = *(const float4*)&sc[base + i0];
        const float me[4] = {mev.x, mev.y, mev.z, mev.w};
        uint32_t cnt[4] = {0, 0, 0, 0};
        if (jb + C <= ibase) {             // all j < i: ties count
            for (int j = 0; j < C; j += 4) {
                const float4 kv = *(const float4*)&keys[j];
                #pragma unroll
                for (int m = 0; m < 4; m++)
                    cnt[m] += (kv.x >= me[m]) + (kv.y >= me[m]) +
                              (kv.z >= me[m]) + (kv.w >= me[m]);
            }
        } else if (jb >= ibase + 1024) {   // all j > i: ties don't count
            for (int j = 0; j < C; j += 4) {
                const float4 kv = *(const float4*)&keys[j];
                #pragma unroll
                for (int m = 0; m < 4; m++)
                    cnt[m] += (kv.x > me[m]) + (kv.y > me[m]) +
                              (kv.z > me[m]) + (kv.w > me[m]);
            }
        } else {                           // diagonal: full stable predicate
            for (int j = 0; j < C; j += 4) {
                const float4 kv = *(const float4*)&keys[j];
                const int jj = jb + j;
                #pragma unroll
                for (int m = 0; m < 4; m++) {
                    const int i = i0 + m;
                    cnt[m] += ((kv.x > me[m]) || (kv.x == me[m] && (jj    ) < i))
                            + ((kv.y > me[m]) || (kv.y == me[m] && (jj + 1) < i))
                            + ((kv.z > me[m]) || (kv.z == me[m] && (jj + 2) < i))
                            + ((kv.w > me[m]) || (kv.w == me[m] && (jj + 3) < i));
                }
            }
        }
        *(ushort4*)&rankp[(size_t)jc * PL + base + i0] =
            make_ushort4((uint16_t)cnt[0], (uint16_t)cnt[1],
                         (uint16_t)cnt[2], (uint16_t)cnt[3]);
    }
}

// Master-block serial section: sum NJC partial planes -> ranks (registers),
// scatter inverse permutation into LDS, flag prefix-scan (SORT_BACK dst),
// softmax (NUMERICS FROZEN, round 5), new scores + pair records.
template<int L>
__device__ __forceinline__ void scanpair_master(const float* __restrict__ sc_cur,
                                                float* __restrict__ sc_nxt,
                                                const uint16_t* __restrict__ rankp,
                                                Rec* __restrict__ rec,
                                                uint16_t* iorlds, uint32_t* part,
                                                int batch, int tid) {
    const int base = batch * LEN0;
    constexpr int R = L / 256;            // 32,16,8,4
    constexpr uint32_t half = L / 2;
    const int i0 = tid * R;

    uint16_t rr[R];
    #pragma unroll
    for (int m = 0; m < R; m += 4) {
        uint32_t s0 = 0, s1 = 0, s2 = 0, s3 = 0;
        #pragma unroll
        for (int c = 0; c < NJC; c++) {
            const ushort4 v = *(const ushort4*)&rankp[(size_t)c * PL + base + i0 + m];
            s0 += v.x; s1 += v.y; s2 += v.z; s3 += v.w;
        }
        rr[m] = (uint16_t)s0; rr[m+1] = (uint16_t)s1;
        rr[m+2] = (uint16_t)s2; rr[m+3] = (uint16_t)s3;
        iorlds[s0] = (uint16_t)(i0 + m);
        iorlds[s1] = (uint16_t)(i0 + m + 1);
        iorlds[s2] = (uint16_t)(i0 + m + 2);
        iorlds[s3] = (uint16_t)(i0 + m + 3);
    }

    uint32_t loc = 0;
    #pragma unroll
    for (int m = 0; m < R; m++) loc += (rr[m] < half) ? 1u : 0u;
    part[tid] = loc;
    __syncthreads();
    for (int off = 1; off < 256; off <<= 1) {    // Hillis-Steele inclusive
        uint32_t v = part[tid];
        uint32_t add = (tid >= off) ? part[tid - off] : 0u;
        __syncthreads();
        part[tid] = v + add;
        __syncthreads();
    }
    uint32_t dst = (tid > 0) ? part[tid - 1] : 0u;

    #pragma unroll
    for (int m = 0; m < R; m++) {
        const uint32_t r = rr[m];
        if (r >= half) continue;
        const int i = i0 + m;
        const uint32_t p = iorlds[(L - 1) - r];

        const float s0 = sc_cur[base + i];
        const float s1 = sc_cur[base + p];
        // np.power(2.0, s): glibc powf (correctly rounded); exp2 in double
        // rounded to f32 reproduces it.
        const float p0 = (float)exp2((double)s0);
        const float p1 = (float)exp2((double)s1);
        const float mx = fmaxf(p0, p1);
        const float d0 = __fsub_rn(p0, mx);
        const float d1 = __fsub_rn(p1, mx);
        const float e0 = npy_expf(d0);
        const float e1 = npy_expf(d1);
        const float den = __fadd_rn(e0, e1);
        const float w0 = __fdiv_rn(e0, den);
        const float w1 = __fdiv_rn(e1, den);
        sc_nxt[base + dst] = __fadd_rn(__fmul_rn(s0, w0), __fmul_rn(s1, w1));

        Rec rc; rc.iA = (uint32_t)i; rc.iB = p; rc.w0 = w0; rc.w1 = w1;
        rec[(size_t)batch * half + dst] = rc;
        dst++;
    }
}

// One level: group rank -> batch-local flag barrier -> master scanpair ->
// gen bump -> waiters proceed.  Relaxed polls, single fences (no per-poll
// cache maintenance, no RMW contention).
template<int L>
__device__ __forceinline__ void level(int lv,
        const float* __restrict__ sc_cur, float* __restrict__ sc_nxt,
        Rec* __restrict__ rec, uint16_t* __restrict__ rankp,
        uint32_t* __restrict__ flags, uint32_t* __restrict__ gens,
        float* keys, uint16_t* iorlds, uint32_t* part,
        int batch, int sub, int tid) {
    rank_group<L>(sc_cur, rankp, keys, batch, sub, tid);
    __syncthreads();
    if (tid == 0) {
        __threadfence();                       // release rankp writes
        relx_st(&flags[(batch * GB + sub) * FPAD], (uint32_t)lv);
    }
    if (sub == 0) {
        if (tid < GB) {
            while (relx_ld(&flags[(batch * GB + tid) * FPAD]) < (uint32_t)lv)
                __builtin_amdgcn_s_sleep(4);
        }
        __syncthreads();
        __threadfence();                       // acquire rankp writes
        scanpair_master<L>(sc_cur, sc_nxt, rankp, rec, iorlds, part, batch, tid);
        __syncthreads();
        if (tid == 0) {
            __threadfence();                   // release sc_nxt/rec writes
            relx_st(&gens[batch * FPAD], (uint32_t)lv);
        }
    } else {
        if (tid == 0) {
            while (relx_ld(&gens[batch * FPAD]) < (uint32_t)lv)
                __builtin_amdgcn_s_sleep(4);
            __threadfence();                   // acquire sc_nxt writes
        }
    }
    __syncthreads();
}

// Whole score pipeline, one kernel, batch-local sync only.
__global__ __launch_bounds__(256, 4)
void k_pipe(const float* __restrict__ scores,
            float* __restrict__ scA, float* __restrict__ scB,
            Rec* __restrict__ rec0, Rec* __restrict__ rec1,
            Rec* __restrict__ rec2, Rec* __restrict__ rec3,
            uint16_t* __restrict__ rankp, uint32_t* __restrict__ sync) {
    __shared__ uint16_t iorlds[8192];   // 16 KiB (master scanpair)
    __shared__ float    keys[512];      //  2 KiB (rank staging)
    __shared__ uint32_t part[256];      //  1 KiB (prefix scan)
    uint32_t* flags = sync;                      // [8][GB] stride FPAD
    uint32_t* gens  = sync + BATCH * GB * FPAD;  // [8]     stride FPAD
    const int bid = blockIdx.x;
    const int tid = threadIdx.x;
    const int batch = bid >> 6;
    const int sub   = bid & (GB - 1);

    level<8192>(1, scores, scA, rec0, rankp, flags, gens, keys, iorlds, part, batch, sub, tid);
    level<4096>(2, scA,    scB, rec1, rankp, flags, gens, keys, iorlds, part, batch, sub, tid);
    level<2048>(3, scB,    scA, rec2, rankp, flags, gens, keys, iorlds, part, batch, sub, tid);
    level<1024>(4, scA,    scB, rec3, rankp, flags, gens, keys, iorlds, part, batch, sub, tid);
    // final scores in scB; pairing tree in rec0..rec3
}

// Final gather: expand 4-level pair tree -> 16 (idx, weight) leaves, then
// out[b,s,:] = sum_k w_k * emb[b, idx_k, :].  (Unchanged — round 9 verified.)
__global__ __launch_bounds__(192)
void k_merge(const float* __restrict__ emb,
             const Rec* __restrict__ rec0, const Rec* __restrict__ rec1,
             const Rec* __restrict__ rec2, const Rec* __restrict__ rec3,
             const float* __restrict__ sc_fin, float* __restrict__ out) {
    __shared__ uint32_t sl[2][16];
    __shared__ float    sw[2][16];
    const int s = blockIdx.x;
    const int b = blockIdx.y;
    const int d = threadIdx.x;

    if (d == 0) {
        const Rec r = rec3[b * 512 + s];
        sl[0][0] = r.iA; sl[0][1] = r.iB;
        sw[0][0] = r.w0; sw[0][1] = r.w1;
    }
    __syncthreads();
    if (d < 2) {
        const Rec r = rec2[b * 1024 + sl[0][d]];
        sl[1][2*d] = r.iA; sl[1][2*d+1] = r.iB;
        sw[1][2*d]   = __fmul_rn(sw[0][d], r.w0);
        sw[1][2*d+1] = __fmul_rn(sw[0][d], r.w1);
    }
    __syncthreads();
    if (d < 4) {
        const Rec r = rec1[b * 2048 + sl[1][d]];
        sl[0][2*d] = r.iA; sl[0][2*d+1] = r.iB;
        sw[0][2*d]   = __fmul_rn(sw[1][d], r.w0);
        sw[0][2*d+1] = __fmul_rn(sw[1][d], r.w1);
    }
    __syncthreads();
    if (d < 8) {
        const Rec r = rec0[b * 4096 + sl[0][d]];   // iA/iB = original rows
        sl[1][2*d] = r.iA; sl[1][2*d+1] = r.iB;
        sw[1][2*d]   = __fmul_rn(sw[0][d], r.w0);
        sw[1][2*d+1] = __fmul_rn(sw[0][d], r.w1);
    }
    __syncthreads();

    const float* ebase = emb + (size_t)b * LEN0 * EMB;
    float4 acc = make_float4(0.f, 0.f, 0.f, 0.f);
    #pragma unroll
    for (int k = 0; k < 16; k++) {
        const float4 v = *(const float4*)(ebase + (size_t)sl[1][k] * EMB + d * 4);
        const float wk = sw[1][k];
        acc.x += wk * v.x; acc.y += wk * v.y; acc.z += wk * v.z; acc.w += wk * v.w;
    }
    *(float4*)(out + ((size_t)b * POOLED + s) * EMB + d * 4) = acc;
    if (d == 0)
        out[(size_t)BATCH * POOLED * EMB + b * POOLED + s] = sc_fin[b * LEN0 + s];
}

extern "C" void kernel_launch(void* const* d_in, const int* in_sizes, int n_in,
                              void* d_out, int out_size, void* d_ws, size_t ws_size,
                              hipStream_t stream) {
    const float* embs   = (const float*)d_in[0];
    const float* scores = (const float*)d_in[1];
    float* out = (float*)d_out;
    char* ws = (char*)d_ws;

    float*    scA   = (float*)(ws + 0x000000);
    float*    scB   = (float*)(ws + 0x040000);
    Rec*      rec0  = (Rec*)(ws + 0x0C0000);
    Rec*      rec1  = (Rec*)(ws + 0x140000);
    Rec*      rec2  = (Rec*)(ws + 0x180000);
    Rec*      rec3  = (Rec*)(ws + 0x1A0000);
    uint16_t* rankp = (uint16_t*)(ws + 0x1C0000);
    uint32_t* sync  = (uint32_t*)(ws + 0x3C0000);

    // flags + gens: (8*64 + 8) * FPAD u32 = 33,280 B, zeroed every call
    hipMemsetAsync(sync, 0, (size_t)(BATCH * GB + BATCH) * FPAD * 4, stream);

    k_pipe<<<GRID, 256, 0, stream>>>(scores, scA, scB,
                                     rec0, rec1, rec2, rec3, rankp, sync);

    k_merge<<<dim3(POOLED, BATCH), 192, 0, stream>>>(embs, rec0, rec1, rec2, rec3,
                                                     scB, out);
}

// Round 11
// 177.022 us; speedup vs baseline: 5.5731x; 1.5759x over previous
//
#include <hip/hip_runtime.h>
#include <stdint.h>

#define BATCH   8
#define LEN0    8192
#define EMB     768
#define POOLED  512    // LEN0 >> 4
#define NJC     16     // j-chunks per level in rank phase
#define PL      (BATCH * LEN0)

struct __align__(16) Rec { uint32_t iA, iB; float w0, w1; };

// ---------------------------------------------------------------------------
// ws layout (bytes):
//   scA    : BATCH*LEN0 f32        @ 0x000000  (256 KiB)
//   scB    : BATCH*LEN0 f32        @ 0x040000
//   rank16 : BATCH*LEN0 u16        @ 0x080000  (128 KiB)
//   ior16  : BATCH*LEN0 u16        @ 0x0A0000  (128 KiB)
//   rec0   : 4096*8 Rec            @ 0x0C0000  (512 KiB)
//   rec1   : 2048*8 Rec            @ 0x140000  (256 KiB)
//   rec2   : 1024*8 Rec            @ 0x180000  (128 KiB)
//   rec3   :  512*8 Rec            @ 0x1A0000  ( 64 KiB)
//   rankp  : NJC planes BATCH*LEN0 u16 @ 0x1C0000 (2 MiB)
//   csum   : BATCH*32 u32          @ 0x3C0000  (1 KiB)
// ---------------------------------------------------------------------------

// Bit-faithful replication of numpy's SIMD float32 exp — DO NOT TOUCH.
// (Round 5 proved this exact sequence makes ranks match the numpy golden.)
__device__ __forceinline__ float npy_expf(float x) {
    const float q = rintf(__fmul_rn(x, 1.44269504088896341f)); // LOG2EF
    float r = __fmaf_rn(q, -0.693359375f, x);       // fnmadd(q, C1, x)
    r = __fmaf_rn(q, 2.12194440e-4f, r);            // fnmadd(q, C2, x)
    const float r2 = __fmul_rn(r, r);
    float p = 1.9875691500E-4f;
    p = __fmaf_rn(p, r, 1.3981999507E-3f);
    p = __fmaf_rn(p, r, 8.3334519073E-3f);
    p = __fmaf_rn(p, r, 4.1665795894E-2f);
    p = __fmaf_rn(p, r, 1.6666665459E-1f);
    p = __fmaf_rn(p, r, 5.0000001201E-1f);
    p = __fmaf_rn(p, r2, r);
    p = __fadd_rn(p, 1.0f);
    const int qi = (int)q;
    const float sc = __uint_as_float((uint32_t)((qi + 127) << 23));
    return __fmul_rn(p, sc);
}

// Chunked rank-by-count, 4 i's/thread vs staged j-chunk, stable ties.
// grid (L/1024, NJC, BATCH).  Partial counts -> rankp plane jc.
__global__ __launch_bounds__(256) void k_rank(const float* __restrict__ sc,
                                              uint16_t* __restrict__ rankp,
                                              int L, int C) {
    __shared__ float keys[512];            // C <= 512
    const int b     = blockIdx.z;
    const int jc    = blockIdx.y;
    const int base  = b * LEN0;
    const int ibase = blockIdx.x * 1024;
    const int jb    = jc * C;
    const int tid   = threadIdx.x;

    for (int j = tid; j < C; j += 256)
        keys[j] = sc[base + jb + j];
    __syncthreads();

    const int i0 = ibase + tid * 4;
    const float4 mev = *(const float4*)&sc[base + i0];
    const float me[4] = {mev.x, mev.y, mev.z, mev.w};
    uint32_t cnt[4] = {0, 0, 0, 0};
    if (jb + C <= ibase) {             // all j < i: ties count
        for (int j = 0; j < C; j += 4) {
            const float4 kv = *(const float4*)&keys[j];
            #pragma unroll
            for (int m = 0; m < 4; m++)
                cnt[m] += (kv.x >= me[m]) + (kv.y >= me[m]) +
                          (kv.z >= me[m]) + (kv.w >= me[m]);
        }
    } else if (jb >= ibase + 1024) {   // all j > i: ties don't count
        for (int j = 0; j < C; j += 4) {
            const float4 kv = *(const float4*)&keys[j];
            #pragma unroll
            for (int m = 0; m < 4; m++)
                cnt[m] += (kv.x > me[m]) + (kv.y > me[m]) +
                          (kv.z > me[m]) + (kv.w > me[m]);
        }
    } else {                           // diagonal: full stable predicate
        for (int j = 0; j < C; j += 4) {
            const float4 kv = *(const float4*)&keys[j];
            const int jj = jb + j;
            #pragma unroll
            for (int m = 0; m < 4; m++) {
                const int i = i0 + m;
                cnt[m] += ((kv.x > me[m]) || (kv.x == me[m] && (jj    ) < i))
                        + ((kv.y > me[m]) || (kv.y == me[m] && (jj + 1) < i))
                        + ((kv.z > me[m]) || (kv.z == me[m] && (jj + 2) < i))
                        + ((kv.w > me[m]) || (kv.w == me[m] && (jj + 3) < i));
            }
        }
    }
    *(ushort4*)&rankp[(size_t)jc * PL + base + i0] =
        make_ushort4((uint16_t)cnt[0], (uint16_t)cnt[1],
                     (uint16_t)cnt[2], (uint16_t)cnt[3]);
}

// Wide: sum NJC partial planes -> rank16; scatter ior16; per-256-chunk
// top-flag sums -> csum.  grid (L/256, BATCH), 256 thr.
__global__ __launch_bounds__(256) void k_sumscatter(const uint16_t* __restrict__ rankp,
                                                    uint16_t* __restrict__ rank16,
                                                    uint16_t* __restrict__ ior16,
                                                    uint32_t* __restrict__ csum,
                                                    int L) {
    __shared__ uint32_t part[256];
    const int b    = blockIdx.y;
    const int base = b * LEN0;
    const int c    = blockIdx.x;
    const int tid  = threadIdx.x;
    const int i    = c * 256 + tid;

    uint32_t r = 0;
    #pragma unroll
    for (int pl = 0; pl < NJC; pl++)
        r += rankp[(size_t)pl * PL + base + i];
    rank16[base + i] = (uint16_t)r;
    ior16[base + r] = (uint16_t)i;

    const uint32_t half = (uint32_t)(L / 2);
    uint32_t flag = (r < half) ? 1u : 0u;
    part[tid] = flag;
    __syncthreads();
    for (int off = 128; off > 0; off >>= 1) {   // tree reduce
        if (tid < off) part[tid] += part[tid + off];
        __syncthreads();
    }
    if (tid == 0) csum[b * 32 + c] = part[0];
}

// Wide pair phase: chunk dst-base from csum, in-block flag scan, softmax
// (NUMERICS FROZEN, round 5), Rec write.  grid (L/256, BATCH), 256 thr.
__global__ __launch_bounds__(256) void k_pairx(const float* __restrict__ sc_cur,
                                               float* __restrict__ sc_nxt,
                                               const uint16_t* __restrict__ rank16,
                                               const uint16_t* __restrict__ ior16,
                                               const uint32_t* __restrict__ csum,
                                               Rec* __restrict__ rec,
                                               int L) {
    __shared__ uint32_t cs[32];
    __shared__ uint32_t part[256];
    const int b    = blockIdx.y;
    const int base = b * LEN0;
    const int c    = blockIdx.x;
    const int tid  = threadIdx.x;
    const int i    = c * 256 + tid;
    const uint32_t half = (uint32_t)(L / 2);

    if (tid < c) cs[tid] = csum[b * 32 + tid];
    const uint32_t r = rank16[base + i];
    const uint32_t flag = (r < half) ? 1u : 0u;
    part[tid] = flag;
    __syncthreads();

    uint32_t dstBase = 0;
    for (int t = 0; t < c; t++) dstBase += cs[t];   // LDS broadcast reads

    for (int off = 1; off < 256; off <<= 1) {       // Hillis-Steele inclusive
        uint32_t v = part[tid];
        uint32_t add = (tid >= off) ? part[tid - off] : 0u;
        __syncthreads();
        part[tid] = v + add;
        __syncthreads();
    }
    if (!flag) return;
    const uint32_t dst = dstBase + part[tid] - 1u;  // exclusive within chunk

    const uint32_t p = ior16[base + (uint32_t)(L - 1) - r];
    const float s0 = sc_cur[base + i];
    const float s1 = sc_cur[base + p];
    // np.power(2.0, s): glibc powf (correctly rounded); exp2 in double
    // rounded to f32 reproduces it.
    const float p0 = (float)exp2((double)s0);
    const float p1 = (float)exp2((double)s1);
    const float mx = fmaxf(p0, p1);
    const float d0 = __fsub_rn(p0, mx);
    const float d1 = __fsub_rn(p1, mx);
    const float e0 = npy_expf(d0);
    const float e1 = npy_expf(d1);
    const float den = __fadd_rn(e0, e1);
    const float w0 = __fdiv_rn(e0, den);
    const float w1 = __fdiv_rn(e1, den);
    sc_nxt[base + dst] = __fadd_rn(__fmul_rn(s0, w0), __fmul_rn(s1, w1));

    Rec rc; rc.iA = (uint32_t)i; rc.iB = p; rc.w0 = w0; rc.w1 = w1;
    rec[(size_t)b * half + dst] = rc;
}

// Final gather: expand 4-level pair tree -> 16 (idx, weight) leaves, then
// out[b,s,:] = sum_k w_k * emb[b, idx_k, :].  (Verified rounds 9/10.)
__global__ __launch_bounds__(192)
void k_merge(const float* __restrict__ emb,
             const Rec* __restrict__ rec0, const Rec* __restrict__ rec1,
             const Rec* __restrict__ rec2, const Rec* __restrict__ rec3,
             const float* __restrict__ sc_fin, float* __restrict__ out) {
    __shared__ uint32_t sl[2][16];
    __shared__ float    sw[2][16];
    const int s = blockIdx.x;
    const int b = blockIdx.y;
    const int d = threadIdx.x;

    if (d == 0) {
        const Rec r = rec3[b * 512 + s];
        sl[0][0] = r.iA; sl[0][1] = r.iB;
        sw[0][0] = r.w0; sw[0][1] = r.w1;
    }
    __syncthreads();
    if (d < 2) {
        const Rec r = rec2[b * 1024 + sl[0][d]];
        sl[1][2*d] = r.iA; sl[1][2*d+1] = r.iB;
        sw[1][2*d]   = __fmul_rn(sw[0][d], r.w0);
        sw[1][2*d+1] = __fmul_rn(sw[0][d], r.w1);
    }
    __syncthreads();
    if (d < 4) {
        const Rec r = rec1[b * 2048 + sl[1][d]];
        sl[0][2*d] = r.iA; sl[0][2*d+1] = r.iB;
        sw[0][2*d]   = __fmul_rn(sw[1][d], r.w0);
        sw[0][2*d+1] = __fmul_rn(sw[1][d], r.w1);
    }
    __syncthreads();
    if (d < 8) {
        const Rec r = rec0[b * 4096 + sl[0][d]];   // iA/iB = original rows
        sl[1][2*d] = r.iA; sl[1][2*d+1] = r.iB;
        sw[1][2*d]   = __fmul_rn(sw[0][d], r.w0);
        sw[1][2*d+1] = __fmul_rn(sw[0][d], r.w1);
    }
    __syncthreads();

    const float* ebase = emb + (size_t)b * LEN0 * EMB;
    float4 acc = make_float4(0.f, 0.f, 0.f, 0.f);
    #pragma unroll
    for (int k = 0; k < 16; k++) {
        const float4 v = *(const float4*)(ebase + (size_t)sl[1][k] * EMB + d * 4);
        const float wk = sw[1][k];
        acc.x += wk * v.x; acc.y += wk * v.y; acc.z += wk * v.z; acc.w += wk * v.w;
    }
    *(float4*)(out + ((size_t)b * POOLED + s) * EMB + d * 4) = acc;
    if (d == 0)
        out[(size_t)BATCH * POOLED * EMB + b * POOLED + s] = sc_fin[b * LEN0 + s];
}

extern "C" void kernel_launch(void* const* d_in, const int* in_sizes, int n_in,
                              void* d_out, int out_size, void* d_ws, size_t ws_size,
                              hipStream_t stream) {
    const float* embs   = (const float*)d_in[0];
    const float* scores = (const float*)d_in[1];
    float* out = (float*)d_out;
    char* ws = (char*)d_ws;

    float*    scA    = (float*)(ws + 0x000000);
    float*    scB    = (float*)(ws + 0x040000);
    uint16_t* rank16 = (uint16_t*)(ws + 0x080000);
    uint16_t* ior16  = (uint16_t*)(ws + 0x0A0000);
    Rec*      rec0   = (Rec*)(ws + 0x0C0000);
    Rec*      rec1   = (Rec*)(ws + 0x140000);
    Rec*      rec2   = (Rec*)(ws + 0x180000);
    Rec*      rec3   = (Rec*)(ws + 0x1A0000);
    uint16_t* rankp  = (uint16_t*)(ws + 0x1C0000);
    uint32_t* csum   = (uint32_t*)(ws + 0x3C0000);

    const float* sc_in[4]  = {scores, scA, scB, scA};
    float*       sc_out[4] = {scA, scB, scA, scB};
    Rec*         recs[4]   = {rec0, rec1, rec2, rec3};

    int L = LEN0;
    for (int l = 0; l < 4; l++) {
        const int C = L / NJC;           // 512,256,128,64
        k_rank<<<dim3(L / 1024, NJC, BATCH), 256, 0, stream>>>(sc_in[l], rankp, L, C);
        k_sumscatter<<<dim3(L / 256, BATCH), 256, 0, stream>>>(rankp, rank16, ior16, csum, L);
        k_pairx<<<dim3(L / 256, BATCH), 256, 0, stream>>>(sc_in[l], sc_out[l],
                                                          rank16, ior16, csum, recs[l], L);
        L >>= 1;
    }

    k_merge<<<dim3(POOLED, BATCH), 192, 0, stream>>>(embs, rec0, rec1, rec2, rec3,
                                                     scB, out);
}